// Round 7
// baseline (554.609 us; speedup 1.0000x reference)
//
#include <hip/hip_runtime.h>
#include <math.h>

#define BG   128            // graphs
#define NPER 1024           // nodes per graph, level 0
#define HDIM 128            // hidden
#define NEDGE (BG * NPER * 8)
#define NMAX (BG * NPER)    // 131072
#define CAP  48             // per-node edge bucket capacity (Poisson(8) tail ~1e-15)
#define PRE  16             // LDS-prefetched edges per node (P(deg>16) ~ 0.4%)

// ---------------------------------------------------------------------------
// p-norms for the three pooling vectors
// ---------------------------------------------------------------------------

__global__ __launch_bounds__(128) void pnorm_kernel(
    const float* __restrict__ p1, const float* __restrict__ p2,
    const float* __restrict__ p3, float* __restrict__ pn) {
  const float* p = blockIdx.x == 0 ? p1 : (blockIdx.x == 1 ? p2 : p3);
  __shared__ float red[128];
  int t = threadIdx.x;
  float v = p[t];
  red[t] = v * v;
  __syncthreads();
  for (int off = 64; off; off >>= 1) {
    if (t < off) red[t] += red[t + off];
    __syncthreads();
  }
  if (t == 0) pn[blockIdx.x] = sqrtf(red[0]);
}

// ---------------------------------------------------------------------------
// L0 in-degree count straight from the input edge list (cnt pre-zeroed)
// ---------------------------------------------------------------------------

__global__ __launch_bounds__(256) void count_kernel(
    const int* __restrict__ ec, int* __restrict__ cnt) {
  int e = blockIdx.x * 256 + threadIdx.x;
  atomicAdd(&cnt[ec[e]], 1);
}

// ---------------------------------------------------------------------------
// prep: dinv from counts; zero fill-cursor; init newid = -1
// ---------------------------------------------------------------------------

__global__ __launch_bounds__(256) void prep_kernel(
    const int* __restrict__ cnt, float* __restrict__ dinv,
    int* __restrict__ cursor, int* __restrict__ newid) {
  int i = blockIdx.x * 256 + threadIdx.x;
  dinv[i] = rsqrtf((float)cnt[i] + 1.0f);
  cursor[i] = 0;
  newid[i] = -1;
}

// ---------------------------------------------------------------------------
// fill: bucket CSR with src row + precomputed coefficient (no indirection left)
// ---------------------------------------------------------------------------

__global__ __launch_bounds__(256) void fill_kernel(
    const int* __restrict__ cr, const int* __restrict__ cc,
    const float* __restrict__ dinv, int* __restrict__ cursor,
    int* __restrict__ src, float* __restrict__ coef) {
  int e = blockIdx.x * 256 + threadIdx.x;
  int c = cc[e];
  if (c >= 0) {
    int r = cr[e];
    int pos = atomicAdd(&cursor[c], 1);
    if (pos < CAP) {
      src[(size_t)c * CAP + pos] = r;
      coef[(size_t)c * CAP + pos] = dinv[r] * dinv[c];
    }
  }
}

// ---------------------------------------------------------------------------
// aggregation: z[c] = sum_e x[src_e]*coef_e + x[c]*dinv[c]^2
// block of 256 = 8 nodes; 32 lanes per node, float4 per lane (512 B/row).
// 8-deep predicated register buffer: all 8 gathers issue before any FMA
// consumes -> 2x the in-flight loads of the round-4 version.
// XCD swizzle keeps each XCD's gathers inside a contiguous graph slice.
// ---------------------------------------------------------------------------

__global__ __launch_bounds__(256) void agg_kernel(
    const float* __restrict__ x, float* __restrict__ z,
    const int* __restrict__ src, const float* __restrict__ coef,
    const int* __restrict__ deg, const float* __restrict__ dinv, int n) {
  int nb = n >> 3;                              // node-octet blocks
  int b = blockIdx.x;
  int blk = (b & 7) * (nb >> 3) + (b >> 3);     // XCD swizzle
  int c0 = blk * 8;
  int t = threadIdx.x;
  int node = t >> 5, lane = t & 31;
  int c = c0 + node;

  __shared__ int s_src[8][PRE];
  __shared__ float s_cf[8][PRE];
  if (t < 128) {
    int nd = t >> 4, e = t & 15;
    s_src[nd][e] = src[(size_t)(c0 + nd) * CAP + e];
    s_cf[nd][e] = coef[(size_t)(c0 + nd) * CAP + e];
  }

  int d = deg[c];
  if (d > CAP) d = CAP;
  float dc = dinv[c];
  float s = dc * dc;
  const float4* x4 = (const float4*)x;
  float4 xs = x4[(size_t)c * 32 + lane];
  float4 a0 = make_float4(xs.x * s, xs.y * s, xs.z * s, xs.w * s);
  float4 a1 = make_float4(0.f, 0.f, 0.f, 0.f);
  __syncthreads();

  int dp = d < PRE ? d : PRE;
  for (int cs = 0; cs < dp; cs += 8) {
    int m = dp - cs;
    if (m > 8) m = 8;
    int sr[8];
    float cf[8];
    #pragma unroll
    for (int i = 0; i < 8; ++i) {               // within PRE bounds always
      sr[i] = s_src[node][cs + i];
      cf[i] = s_cf[node][cs + i];
    }
    float4 v[8];
    #pragma unroll
    for (int i = 0; i < 8; ++i)
      if (i < m) v[i] = x4[(size_t)sr[i] * 32 + lane];
    #pragma unroll
    for (int i = 0; i < 8; ++i)
      if (i < m) {
        if (i & 1) {
          a1.x = fmaf(v[i].x, cf[i], a1.x); a1.y = fmaf(v[i].y, cf[i], a1.y);
          a1.z = fmaf(v[i].z, cf[i], a1.z); a1.w = fmaf(v[i].w, cf[i], a1.w);
        } else {
          a0.x = fmaf(v[i].x, cf[i], a0.x); a0.y = fmaf(v[i].y, cf[i], a0.y);
          a0.z = fmaf(v[i].z, cf[i], a0.z); a0.w = fmaf(v[i].w, cf[i], a0.w);
        }
      }
  }
  for (int e = PRE; e < d; ++e) {               // rare tail (deg > 16)
    int r0 = src[(size_t)c * CAP + e];
    float f0 = coef[(size_t)c * CAP + e];
    float4 v0 = x4[(size_t)r0 * 32 + lane];
    a0.x = fmaf(v0.x, f0, a0.x); a0.y = fmaf(v0.y, f0, a0.y);
    a0.z = fmaf(v0.z, f0, a0.z); a0.w = fmaf(v0.w, f0, a0.w);
  }
  float4 o = make_float4(a0.x + a1.x, a0.y + a1.y, a0.z + a1.z, a0.w + a1.w);
  ((float4*)z)[(size_t)c * 32 + lane] = o;
}

// ---------------------------------------------------------------------------
// conv: h = relu(z @ W + b), in-place on zh; also score[row] = h . p
// tile: 64 rows x 128 cols, block 256 (8 rows x 4 cols per thread —
// the W-load cost is amortized over 8 rows; round-6 showed 4 rows is
// load-issue-bound)
// ---------------------------------------------------------------------------

__global__ __launch_bounds__(256) void conv_kernel(
    float* __restrict__ zh, const float* __restrict__ W,
    const float* __restrict__ bias, const float* __restrict__ p,
    float* __restrict__ score) {
  __shared__ float sZ[64 * HDIM];
  int tid = threadIdx.x;
  size_t base = (size_t)blockIdx.x * 64 * HDIM;
  float4* sZ4 = (float4*)sZ;
  const float4* g4 = (const float4*)(zh + base);
  #pragma unroll
  for (int i = 0; i < 8; ++i) sZ4[i * 256 + tid] = g4[i * 256 + tid];
  __syncthreads();

  int col_t = tid & 31;
  int row_t = tid >> 5;
  int r0 = row_t * 8;
  const float4* W4 = (const float4*)W;

  float acc[8][4];
  #pragma unroll
  for (int r = 0; r < 8; ++r)
    #pragma unroll
    for (int c = 0; c < 4; ++c) acc[r][c] = 0.f;

  for (int k4 = 0; k4 < 32; ++k4) {
    float4 w0 = W4[(k4 * 4 + 0) * 32 + col_t];
    float4 w1 = W4[(k4 * 4 + 1) * 32 + col_t];
    float4 w2 = W4[(k4 * 4 + 2) * 32 + col_t];
    float4 w3 = W4[(k4 * 4 + 3) * 32 + col_t];
    #pragma unroll
    for (int r = 0; r < 8; ++r) {
      float4 zr = sZ4[(r0 + r) * 32 + k4];
      acc[r][0] = fmaf(zr.x, w0.x, acc[r][0]);
      acc[r][1] = fmaf(zr.x, w0.y, acc[r][1]);
      acc[r][2] = fmaf(zr.x, w0.z, acc[r][2]);
      acc[r][3] = fmaf(zr.x, w0.w, acc[r][3]);
      acc[r][0] = fmaf(zr.y, w1.x, acc[r][0]);
      acc[r][1] = fmaf(zr.y, w1.y, acc[r][1]);
      acc[r][2] = fmaf(zr.y, w1.z, acc[r][2]);
      acc[r][3] = fmaf(zr.y, w1.w, acc[r][3]);
      acc[r][0] = fmaf(zr.z, w2.x, acc[r][0]);
      acc[r][1] = fmaf(zr.z, w2.y, acc[r][1]);
      acc[r][2] = fmaf(zr.z, w2.z, acc[r][2]);
      acc[r][3] = fmaf(zr.z, w2.w, acc[r][3]);
      acc[r][0] = fmaf(zr.w, w3.x, acc[r][0]);
      acc[r][1] = fmaf(zr.w, w3.y, acc[r][1]);
      acc[r][2] = fmaf(zr.w, w3.z, acc[r][2]);
      acc[r][3] = fmaf(zr.w, w3.w, acc[r][3]);
    }
  }

  float4 bv = ((const float4*)bias)[col_t];
  float4 pv = ((const float4*)p)[col_t];
  float4* out4 = (float4*)(zh + base);
  #pragma unroll
  for (int r = 0; r < 8; ++r) {
    float hx = fmaxf(acc[r][0] + bv.x, 0.f);
    float hy = fmaxf(acc[r][1] + bv.y, 0.f);
    float hz = fmaxf(acc[r][2] + bv.z, 0.f);
    float hw = fmaxf(acc[r][3] + bv.w, 0.f);
    float part = hx * pv.x + hy * pv.y + hz * pv.z + hw * pv.w;
    #pragma unroll
    for (int sft = 1; sft < 32; sft <<= 1) part += __shfl_xor(part, sft);
    out4[(r0 + r) * 32 + col_t] = make_float4(hx, hy, hz, hw);
    if (col_t == 0) score[blockIdx.x * 64 + r0 + r] = part;
  }
}

// ---------------------------------------------------------------------------
// per-graph top-K (K = P/2): P-thread bitonic sort, one element per thread,
// one compare-exchange pass per stage (55 passes at P=1024).
// descending, tie-break lower index. Also zeroes cnt for next layer.
// ---------------------------------------------------------------------------

__global__ __launch_bounds__(1024) void topk_kernel(
    const float* __restrict__ score, const float* __restrict__ pnorm,
    int* __restrict__ sel, float* __restrict__ tanhv, int* __restrict__ newid,
    int* __restrict__ cnt_next, int P, int K) {
  __shared__ float sv[1024];
  __shared__ int si[1024];
  int g = blockIdx.x;
  int t = threadIdx.x;
  if (t < K) cnt_next[g * K + t] = 0;
  sv[t] = score[(size_t)g * P + t];
  si[t] = t;
  for (int size = 2; size <= P; size <<= 1) {
    for (int stride = size >> 1; stride; stride >>= 1) {
      __syncthreads();
      int j = t ^ stride;
      if (j > t) {
        float a = sv[t], b = sv[j];
        int ia = si[t], ib = si[j];
        bool tFirst = (a > b) || (a == b && ia < ib);
        bool up = ((t & size) == 0);
        if (up ? !tFirst : tFirst) {
          sv[t] = b; sv[j] = a;
          si[t] = ib; si[j] = ia;
        }
      }
    }
  }
  __syncthreads();
  if (t < K) {
    float v = sv[t];
    int oldg = g * P + si[t];
    int newg = g * K + t;
    sel[newg] = oldg;
    tanhv[newg] = tanhf(v / pnorm[0]);
    newid[oldg] = newg;
  }
}

// ---------------------------------------------------------------------------
// pool gather: xo[j] = h[sel[j]] * tanhv[j] for a 16-row chunk; float4 lanes.
// grid = BG * (K/16); block 256: lane = t&31 -> channels 4*lane, slot = t>>5
// covers rows {slot, slot+8}; per-chunk partial max/sum to pred
// ---------------------------------------------------------------------------

__global__ __launch_bounds__(256) void pool_gather_kernel(
    const float* __restrict__ h, const int* __restrict__ sel,
    const float* __restrict__ tanhv, float* __restrict__ xo,
    float* __restrict__ pred, int K, int lc) {
  __shared__ int s_sel[16];
  __shared__ float s_th[16];
  __shared__ float4 smx[8][32], ssm[8][32];
  int b = blockIdx.x;
  int g = b >> lc;
  int chunk = b & ((1 << lc) - 1);
  int t = threadIdx.x;
  int j0 = chunk * 16;
  if (t < 16) {
    s_sel[t] = sel[g * K + j0 + t];
    s_th[t] = tanhv[g * K + j0 + t];
  }
  __syncthreads();
  int lane = t & 31, slot = t >> 5;
  const float4* h4 = (const float4*)h;
  float4* xo4 = (float4*)xo;
  float4 mx = make_float4(-INFINITY, -INFINITY, -INFINITY, -INFINITY);
  float4 sm = make_float4(0.f, 0.f, 0.f, 0.f);
  #pragma unroll
  for (int i = 0; i < 2; ++i) {
    int j = slot + i * 8;
    float th = s_th[j];
    float4 v = h4[(size_t)s_sel[j] * 32 + lane];
    v.x *= th; v.y *= th; v.z *= th; v.w *= th;
    xo4[(size_t)(g * K + j0 + j) * 32 + lane] = v;
    mx.x = fmaxf(mx.x, v.x); mx.y = fmaxf(mx.y, v.y);
    mx.z = fmaxf(mx.z, v.z); mx.w = fmaxf(mx.w, v.w);
    sm.x += v.x; sm.y += v.y; sm.z += v.z; sm.w += v.w;
  }
  smx[slot][lane] = mx;
  ssm[slot][lane] = sm;
  __syncthreads();
  if (slot == 0) {
    #pragma unroll
    for (int s2 = 1; s2 < 8; ++s2) {
      float4 m2 = smx[s2][lane], s3 = ssm[s2][lane];
      mx.x = fmaxf(mx.x, m2.x); mx.y = fmaxf(mx.y, m2.y);
      mx.z = fmaxf(mx.z, m2.z); mx.w = fmaxf(mx.w, m2.w);
      sm.x += s3.x; sm.y += s3.y; sm.z += s3.z; sm.w += s3.w;
    }
    float4* pred4 = (float4*)pred;
    pred4[(size_t)(g * 32 + chunk) * 64 + lane] = mx;
    pred4[(size_t)(g * 32 + chunk) * 64 + 32 + lane] = sm;
  }
}

// ---------------------------------------------------------------------------
// pool combine: reduce C chunk-partials per graph, accumulate into out
// block = 64 threads: t<32 -> max channels 4t.., t>=32 -> sum channels
// ---------------------------------------------------------------------------

__global__ __launch_bounds__(64) void pool_combine_kernel(
    const float* __restrict__ pred, float* __restrict__ out, int K, int C) {
  int g = blockIdx.x;
  int t = threadIdx.x;
  const float4* pred4 = (const float4*)pred;
  float4* out4 = (float4*)out;
  if (t < 32) {
    float4 mx = make_float4(-INFINITY, -INFINITY, -INFINITY, -INFINITY);
    for (int c = 0; c < C; ++c) {
      float4 v = pred4[(size_t)(g * 32 + c) * 64 + t];
      mx.x = fmaxf(mx.x, v.x); mx.y = fmaxf(mx.y, v.y);
      mx.z = fmaxf(mx.z, v.z); mx.w = fmaxf(mx.w, v.w);
    }
    float4 o = out4[g * 64 + t];
    o.x += mx.x; o.y += mx.y; o.z += mx.z; o.w += mx.w;
    out4[g * 64 + t] = o;
  } else {
    int l = t - 32;
    float4 sm = make_float4(0.f, 0.f, 0.f, 0.f);
    for (int c = 0; c < C; ++c) {
      float4 v = pred4[(size_t)(g * 32 + c) * 64 + 32 + l];
      sm.x += v.x; sm.y += v.y; sm.z += v.z; sm.w += v.w;
    }
    float inv = 1.0f / (float)K;
    float4 o = out4[g * 64 + 32 + l];
    o.x += sm.x * inv; o.y += sm.y * inv; o.z += sm.z * inv; o.w += sm.w * inv;
    out4[g * 64 + 32 + l] = o;
  }
}

// ---------------------------------------------------------------------------
// fused relabel + count for next layer (cnt zeroed by topk); separate in/out
// so L0 can read the pristine inputs and write the mutable arrays
// ---------------------------------------------------------------------------

__global__ __launch_bounds__(256) void relabel_count_kernel(
    const int* __restrict__ in_r, const int* __restrict__ in_c,
    int* __restrict__ out_r, int* __restrict__ out_c,
    const int* __restrict__ newid, int* __restrict__ cnt) {
  int e = blockIdx.x * 256 + threadIdx.x;
  int r = in_r[e];
  if (r < 0) {
    out_r[e] = -1;
    out_c[e] = -1;
    return;
  }
  int nr = newid[r];
  int nc = newid[in_c[e]];
  if (nr < 0 || nc < 0) {
    out_r[e] = -1;
    out_c[e] = -1;
  } else {
    out_r[e] = nr;
    out_c[e] = nc;
    atomicAdd(&cnt[nc], 1);
  }
}

// ---------------------------------------------------------------------------
// launch
// ---------------------------------------------------------------------------

extern "C" void kernel_launch(void* const* d_in, const int* in_sizes, int n_in,
                              void* d_out, int out_size, void* d_ws, size_t ws_size,
                              hipStream_t stream) {
  const float* x0 = (const float*)d_in[0];
  const int* erow = (const int*)d_in[1];
  const int* ecol = (const int*)d_in[2];
  const float* Wm[3] = {(const float*)d_in[3], (const float*)d_in[6], (const float*)d_in[9]};
  const float* bm[3] = {(const float*)d_in[4], (const float*)d_in[7], (const float*)d_in[10]};
  const float* pm[3] = {(const float*)d_in[5], (const float*)d_in[8], (const float*)d_in[11]};

  char* w = (char*)d_ws;
  size_t off = 0;
  auto alloc = [&](size_t bytes) -> void* {
    void* ptr = w + off;
    off = (off + bytes + 255) & ~(size_t)255;
    return ptr;
  };
  int* cur_row = (int*)alloc((size_t)NEDGE * 4);
  int* cur_col = (int*)alloc((size_t)NEDGE * 4);
  int* src     = (int*)alloc((size_t)NMAX * CAP * 4);
  float* coef  = (float*)alloc((size_t)NMAX * CAP * 4);
  int* cnt     = (int*)alloc((size_t)NMAX * 4);
  int* cursor  = (int*)alloc((size_t)NMAX * 4);
  float* dinv  = (float*)alloc((size_t)NMAX * 4);
  int* newid   = (int*)alloc((size_t)NMAX * 4);
  float* score = (float*)alloc((size_t)NMAX * 4);
  int* sel     = (int*)alloc((size_t)BG * 512 * 4);
  float* tanhv = (float*)alloc((size_t)BG * 512 * 4);
  float* pn    = (float*)alloc(256);
  float* pred  = (float*)alloc((size_t)BG * 32 * 256 * 4);
  float* zh    = (float*)alloc((size_t)NMAX * HDIM * 4);
  float* x1    = (float*)alloc((size_t)BG * 512 * HDIM * 4);
  float* x2    = (float*)alloc((size_t)BG * 256 * HDIM * 4);
  float* x3    = (float*)alloc((size_t)BG * 128 * HDIM * 4);

  hipMemsetAsync(d_out, 0, (size_t)out_size * 4, stream);
  hipMemsetAsync(cnt, 0, (size_t)NMAX * 4, stream);
  pnorm_kernel<<<3, 128, 0, stream>>>(pm[0], pm[1], pm[2], pn);
  count_kernel<<<NEDGE / 256, 256, 0, stream>>>(ecol, cnt);

  const float* xin = x0;
  float* xout[3] = {x1, x2, x3};
  int Ps[3] = {1024, 512, 256};
  int LCs[3] = {5, 4, 3};     // log2(K/16)

  for (int L = 0; L < 3; ++L) {
    int P = Ps[L];
    int K = P >> 1;
    int n = BG * P;
    int lc = LCs[L];
    int C = 1 << lc;
    const int* in_r = (L == 0) ? erow : cur_row;
    const int* in_c = (L == 0) ? ecol : cur_col;

    prep_kernel<<<n / 256, 256, 0, stream>>>(cnt, dinv, cursor, newid);
    fill_kernel<<<NEDGE / 256, 256, 0, stream>>>(in_r, in_c, dinv, cursor, src, coef);
    agg_kernel<<<n / 8, 256, 0, stream>>>(xin, zh, src, coef, cursor, dinv, n);
    conv_kernel<<<n / 64, 256, 0, stream>>>(zh, Wm[L], bm[L], pm[L], score);
    topk_kernel<<<BG, P, 0, stream>>>(score, pn + L, sel, tanhv, newid, cnt, P, K);
    pool_gather_kernel<<<BG * C, 256, 0, stream>>>(zh, sel, tanhv, xout[L], pred, K, lc);
    pool_combine_kernel<<<BG, 64, 0, stream>>>(pred, (float*)d_out, K, C);
    if (L < 2) relabel_count_kernel<<<NEDGE / 256, 256, 0, stream>>>(
        in_r, in_c, cur_row, cur_col, newid, cnt);
    xin = xout[L];
  }
}

// Round 8
// 529.917 us; speedup vs baseline: 1.0466x; 1.0466x over previous
//
#include <hip/hip_runtime.h>
#include <math.h>

#define BG   128            // graphs
#define NPER 1024           // nodes per graph, level 0
#define HDIM 128            // hidden
#define NEDGE (BG * NPER * 8)
#define NMAX (BG * NPER)    // 131072
#define CAP  48             // per-node edge capacity (Poisson(8) tail ~1e-15)
#define PRE  16             // packed-meta entries per node (P(deg>16) ~ 0.4%)
#define CH   32             // channels per agg chunk
#define CHUNKS 4            // 128 / CH

// ---------------------------------------------------------------------------
// p-norms for the three pooling vectors
// ---------------------------------------------------------------------------

__global__ __launch_bounds__(128) void pnorm_kernel(
    const float* __restrict__ p1, const float* __restrict__ p2,
    const float* __restrict__ p3, float* __restrict__ pn) {
  const float* p = blockIdx.x == 0 ? p1 : (blockIdx.x == 1 ? p2 : p3);
  __shared__ float red[128];
  int t = threadIdx.x;
  float v = p[t];
  red[t] = v * v;
  __syncthreads();
  for (int off = 64; off; off >>= 1) {
    if (t < off) red[t] += red[t + off];
    __syncthreads();
  }
  if (t == 0) pn[blockIdx.x] = sqrtf(red[0]);
}

// ---------------------------------------------------------------------------
// L0 in-degree count straight from the input edge list (cnt pre-zeroed)
// ---------------------------------------------------------------------------

__global__ __launch_bounds__(256) void count_kernel(
    const int* __restrict__ ec, int* __restrict__ cnt) {
  int e = blockIdx.x * 256 + threadIdx.x;
  atomicAdd(&cnt[ec[e]], 1);
}

// ---------------------------------------------------------------------------
// prep: dinv from counts; zero fill-cursor; init newid = -1
// ---------------------------------------------------------------------------

__global__ __launch_bounds__(256) void prep_kernel(
    const int* __restrict__ cnt, float* __restrict__ dinv,
    int* __restrict__ cursor, int* __restrict__ newid) {
  int i = blockIdx.x * 256 + threadIdx.x;
  dinv[i] = rsqrtf((float)cnt[i] + 1.0f);
  cursor[i] = 0;
  newid[i] = -1;
}

// ---------------------------------------------------------------------------
// fill: packed per-node meta (graph-LOCAL src, coef) for the first PRE edges;
// overflow (rare) to srcext/cfext. mask = nodes-per-graph - 1.
// ---------------------------------------------------------------------------

__global__ __launch_bounds__(256) void fill_kernel(
    const int* __restrict__ cr, const int* __restrict__ cc,
    const float* __restrict__ dinv, int* __restrict__ cursor,
    int2* __restrict__ meta16, int* __restrict__ srcext,
    float* __restrict__ cfext, int mask) {
  int e = blockIdx.x * 256 + threadIdx.x;
  int c = cc[e];
  if (c >= 0) {
    int r = cr[e];
    int pos = atomicAdd(&cursor[c], 1);
    float cf = dinv[r] * dinv[c];
    int rl = r & mask;                  // graph-local row index
    if (pos < PRE) {
      meta16[(size_t)c * PRE + pos] = make_int2(rl, __float_as_int(cf));
    } else if (pos < CAP) {
      srcext[(size_t)c * CAP + pos] = rl;
      cfext[(size_t)c * CAP + pos] = cf;
    }
  }
}

// ---------------------------------------------------------------------------
// LDS-resident aggregation: block = (graph, 32-channel chunk).
//  stage x[graph][:, chunk] (npg x 128 B) + dinv -> LDS (coalesced, read ONCE)
//  per 128-dst pass: stage packed meta (16 KB) -> 8 lanes/dst gather rows from
//  LDS via ds_read_b128 (structural-minimum bank traffic) and FMA.
// Replaces the scattered-vmem gather that was pinned at ~10 B/cyc/CU.
// dynamic LDS: npg*32*4 + npg*4 + 16384 bytes (L0: 148 KB).
// ---------------------------------------------------------------------------

extern __shared__ float ldsbuf[];

__global__ __launch_bounds__(1024) void agg_lds_kernel(
    const float* __restrict__ x, float* __restrict__ z,
    const int2* __restrict__ meta16, const int* __restrict__ srcext,
    const float* __restrict__ cfext, const int* __restrict__ deg,
    const float* __restrict__ dinv, int npg) {
  float* sX = ldsbuf;                          // [npg][32]
  float* sDinv = sX + npg * 32;                // [npg]
  int2* sMeta = (int2*)(sDinv + npg);          // [128][PRE]
  int g = blockIdx.x >> 2;
  int chunk = blockIdx.x & 3;
  int t = threadIdx.x;
  int base = g * npg;

  const float4* x4 = (const float4*)x;
  float4* sX4 = (float4*)sX;
  for (int i = t; i < npg * 8; i += 1024) {
    int r = i >> 3, l8 = i & 7;
    sX4[i] = x4[(size_t)(base + r) * 32 + chunk * 8 + l8];
  }
  for (int i = t; i < npg; i += 1024) sDinv[i] = dinv[base + i];
  __syncthreads();

  int passes = npg >> 7;
  int dl = t >> 3, l = t & 7;                  // dst-local 0..127, lane 0..7
  for (int pass = 0; pass < passes; ++pass) {
    // stage meta for this pass's 128 dst (128*16*8 B = 16 KB)
    {
      const int4* gm = (const int4*)(meta16 + (size_t)(base + pass * 128) * PRE);
      ((int4*)sMeta)[t] = gm[t];
    }
    __syncthreads();
    int dst = pass * 128 + dl;
    int node = base + dst;
    int d = deg[node];
    if (d > CAP) d = CAP;
    float dc = sDinv[dst];
    float s0 = dc * dc;
    float4 row = sX4[dst * 8 + l];
    float4 a0 = make_float4(row.x * s0, row.y * s0, row.z * s0, row.w * s0);
    float4 a1 = make_float4(0.f, 0.f, 0.f, 0.f);
    int dp = d < PRE ? d : PRE;
    const int2* m = &sMeta[dl * PRE];
    const int4* m4 = (const int4*)m;
    int e = 0;
    for (; e + 1 < dp; e += 2) {               // 2 edges per b128 meta read
      int4 q = m4[e >> 1];
      float4 v0 = sX4[q.x * 8 + l];
      float4 v1 = sX4[q.z * 8 + l];
      float c0 = __int_as_float(q.y), c1 = __int_as_float(q.w);
      a0.x = fmaf(v0.x, c0, a0.x); a0.y = fmaf(v0.y, c0, a0.y);
      a0.z = fmaf(v0.z, c0, a0.z); a0.w = fmaf(v0.w, c0, a0.w);
      a1.x = fmaf(v1.x, c1, a1.x); a1.y = fmaf(v1.y, c1, a1.y);
      a1.z = fmaf(v1.z, c1, a1.z); a1.w = fmaf(v1.w, c1, a1.w);
    }
    if (e < dp) {
      int2 pr = m[e];
      float4 v0 = sX4[pr.x * 8 + l];
      float c0 = __int_as_float(pr.y);
      a0.x = fmaf(v0.x, c0, a0.x); a0.y = fmaf(v0.y, c0, a0.y);
      a0.z = fmaf(v0.z, c0, a0.z); a0.w = fmaf(v0.w, c0, a0.w);
    }
    for (int e2 = PRE; e2 < d; ++e2) {         // rare overflow (deg > 16)
      int rl = srcext[(size_t)node * CAP + e2];
      float cf = cfext[(size_t)node * CAP + e2];
      float4 v0 = sX4[rl * 8 + l];
      a0.x = fmaf(v0.x, cf, a0.x); a0.y = fmaf(v0.y, cf, a0.y);
      a0.z = fmaf(v0.z, cf, a0.z); a0.w = fmaf(v0.w, cf, a0.w);
    }
    float4 o = make_float4(a0.x + a1.x, a0.y + a1.y, a0.z + a1.z, a0.w + a1.w);
    ((float4*)z)[(size_t)node * 32 + chunk * 8 + l] = o;
    __syncthreads();                           // before next pass's meta stage
  }
}

// ---------------------------------------------------------------------------
// conv: h = relu(z @ W + b), in-place on zh; also score[row] = h . p
// tile: 64 rows x 128 cols, block 256 (8 rows x 4 cols per thread)
// ---------------------------------------------------------------------------

__global__ __launch_bounds__(256) void conv_kernel(
    float* __restrict__ zh, const float* __restrict__ W,
    const float* __restrict__ bias, const float* __restrict__ p,
    float* __restrict__ score) {
  __shared__ float sZ[64 * HDIM];
  int tid = threadIdx.x;
  size_t base = (size_t)blockIdx.x * 64 * HDIM;
  float4* sZ4 = (float4*)sZ;
  const float4* g4 = (const float4*)(zh + base);
  #pragma unroll
  for (int i = 0; i < 8; ++i) sZ4[i * 256 + tid] = g4[i * 256 + tid];
  __syncthreads();

  int col_t = tid & 31;
  int row_t = tid >> 5;
  int r0 = row_t * 8;
  const float4* W4 = (const float4*)W;

  float acc[8][4];
  #pragma unroll
  for (int r = 0; r < 8; ++r)
    #pragma unroll
    for (int c = 0; c < 4; ++c) acc[r][c] = 0.f;

  for (int k4 = 0; k4 < 32; ++k4) {
    float4 w0 = W4[(k4 * 4 + 0) * 32 + col_t];
    float4 w1 = W4[(k4 * 4 + 1) * 32 + col_t];
    float4 w2 = W4[(k4 * 4 + 2) * 32 + col_t];
    float4 w3 = W4[(k4 * 4 + 3) * 32 + col_t];
    #pragma unroll
    for (int r = 0; r < 8; ++r) {
      float4 zr = sZ4[(r0 + r) * 32 + k4];
      acc[r][0] = fmaf(zr.x, w0.x, acc[r][0]);
      acc[r][1] = fmaf(zr.x, w0.y, acc[r][1]);
      acc[r][2] = fmaf(zr.x, w0.z, acc[r][2]);
      acc[r][3] = fmaf(zr.x, w0.w, acc[r][3]);
      acc[r][0] = fmaf(zr.y, w1.x, acc[r][0]);
      acc[r][1] = fmaf(zr.y, w1.y, acc[r][1]);
      acc[r][2] = fmaf(zr.y, w1.z, acc[r][2]);
      acc[r][3] = fmaf(zr.y, w1.w, acc[r][3]);
      acc[r][0] = fmaf(zr.z, w2.x, acc[r][0]);
      acc[r][1] = fmaf(zr.z, w2.y, acc[r][1]);
      acc[r][2] = fmaf(zr.z, w2.z, acc[r][2]);
      acc[r][3] = fmaf(zr.z, w2.w, acc[r][3]);
      acc[r][0] = fmaf(zr.w, w3.x, acc[r][0]);
      acc[r][1] = fmaf(zr.w, w3.y, acc[r][1]);
      acc[r][2] = fmaf(zr.w, w3.z, acc[r][2]);
      acc[r][3] = fmaf(zr.w, w3.w, acc[r][3]);
    }
  }

  float4 bv = ((const float4*)bias)[col_t];
  float4 pv = ((const float4*)p)[col_t];
  float4* out4 = (float4*)(zh + base);
  #pragma unroll
  for (int r = 0; r < 8; ++r) {
    float hx = fmaxf(acc[r][0] + bv.x, 0.f);
    float hy = fmaxf(acc[r][1] + bv.y, 0.f);
    float hz = fmaxf(acc[r][2] + bv.z, 0.f);
    float hw = fmaxf(acc[r][3] + bv.w, 0.f);
    float part = hx * pv.x + hy * pv.y + hz * pv.z + hw * pv.w;
    #pragma unroll
    for (int sft = 1; sft < 32; sft <<= 1) part += __shfl_xor(part, sft);
    out4[(r0 + r) * 32 + col_t] = make_float4(hx, hy, hz, hw);
    if (col_t == 0) score[blockIdx.x * 64 + r0 + r] = part;
  }
}

// ---------------------------------------------------------------------------
// per-graph top-K (K = P/2): P-thread bitonic sort, one element per thread.
// descending, tie-break lower index. Also zeroes cnt for next layer.
// ---------------------------------------------------------------------------

__global__ __launch_bounds__(1024) void topk_kernel(
    const float* __restrict__ score, const float* __restrict__ pnorm,
    int* __restrict__ sel, float* __restrict__ tanhv, int* __restrict__ newid,
    int* __restrict__ cnt_next, int P, int K) {
  __shared__ float sv[1024];
  __shared__ int si[1024];
  int g = blockIdx.x;
  int t = threadIdx.x;
  if (t < K) cnt_next[g * K + t] = 0;
  sv[t] = score[(size_t)g * P + t];
  si[t] = t;
  for (int size = 2; size <= P; size <<= 1) {
    for (int stride = size >> 1; stride; stride >>= 1) {
      __syncthreads();
      int j = t ^ stride;
      if (j > t) {
        float a = sv[t], b = sv[j];
        int ia = si[t], ib = si[j];
        bool tFirst = (a > b) || (a == b && ia < ib);
        bool up = ((t & size) == 0);
        if (up ? !tFirst : tFirst) {
          sv[t] = b; sv[j] = a;
          si[t] = ib; si[j] = ia;
        }
      }
    }
  }
  __syncthreads();
  if (t < K) {
    float v = sv[t];
    int oldg = g * P + si[t];
    int newg = g * K + t;
    sel[newg] = oldg;
    tanhv[newg] = tanhf(v / pnorm[0]);
    newid[oldg] = newg;
  }
}

// ---------------------------------------------------------------------------
// pool gather: xo[j] = h[sel[j]] * tanhv[j] for a 16-row chunk; float4 lanes.
// ---------------------------------------------------------------------------

__global__ __launch_bounds__(256) void pool_gather_kernel(
    const float* __restrict__ h, const int* __restrict__ sel,
    const float* __restrict__ tanhv, float* __restrict__ xo,
    float* __restrict__ pred, int K, int lc) {
  __shared__ int s_sel[16];
  __shared__ float s_th[16];
  __shared__ float4 smx[8][32], ssm[8][32];
  int b = blockIdx.x;
  int g = b >> lc;
  int chunk = b & ((1 << lc) - 1);
  int t = threadIdx.x;
  int j0 = chunk * 16;
  if (t < 16) {
    s_sel[t] = sel[g * K + j0 + t];
    s_th[t] = tanhv[g * K + j0 + t];
  }
  __syncthreads();
  int lane = t & 31, slot = t >> 5;
  const float4* h4 = (const float4*)h;
  float4* xo4 = (float4*)xo;
  float4 mx = make_float4(-INFINITY, -INFINITY, -INFINITY, -INFINITY);
  float4 sm = make_float4(0.f, 0.f, 0.f, 0.f);
  #pragma unroll
  for (int i = 0; i < 2; ++i) {
    int j = slot + i * 8;
    float th = s_th[j];
    float4 v = h4[(size_t)s_sel[j] * 32 + lane];
    v.x *= th; v.y *= th; v.z *= th; v.w *= th;
    xo4[(size_t)(g * K + j0 + j) * 32 + lane] = v;
    mx.x = fmaxf(mx.x, v.x); mx.y = fmaxf(mx.y, v.y);
    mx.z = fmaxf(mx.z, v.z); mx.w = fmaxf(mx.w, v.w);
    sm.x += v.x; sm.y += v.y; sm.z += v.z; sm.w += v.w;
  }
  smx[slot][lane] = mx;
  ssm[slot][lane] = sm;
  __syncthreads();
  if (slot == 0) {
    #pragma unroll
    for (int s2 = 1; s2 < 8; ++s2) {
      float4 m2 = smx[s2][lane], s3 = ssm[s2][lane];
      mx.x = fmaxf(mx.x, m2.x); mx.y = fmaxf(mx.y, m2.y);
      mx.z = fmaxf(mx.z, m2.z); mx.w = fmaxf(mx.w, m2.w);
      sm.x += s3.x; sm.y += s3.y; sm.z += s3.z; sm.w += s3.w;
    }
    float4* pred4 = (float4*)pred;
    pred4[(size_t)(g * 32 + chunk) * 64 + lane] = mx;
    pred4[(size_t)(g * 32 + chunk) * 64 + 32 + lane] = sm;
  }
}

// ---------------------------------------------------------------------------
// pool combine: reduce C chunk-partials per graph, accumulate into out
// ---------------------------------------------------------------------------

__global__ __launch_bounds__(64) void pool_combine_kernel(
    const float* __restrict__ pred, float* __restrict__ out, int K, int C) {
  int g = blockIdx.x;
  int t = threadIdx.x;
  const float4* pred4 = (const float4*)pred;
  float4* out4 = (float4*)out;
  if (t < 32) {
    float4 mx = make_float4(-INFINITY, -INFINITY, -INFINITY, -INFINITY);
    for (int c = 0; c < C; ++c) {
      float4 v = pred4[(size_t)(g * 32 + c) * 64 + t];
      mx.x = fmaxf(mx.x, v.x); mx.y = fmaxf(mx.y, v.y);
      mx.z = fmaxf(mx.z, v.z); mx.w = fmaxf(mx.w, v.w);
    }
    float4 o = out4[g * 64 + t];
    o.x += mx.x; o.y += mx.y; o.z += mx.z; o.w += mx.w;
    out4[g * 64 + t] = o;
  } else {
    int l = t - 32;
    float4 sm = make_float4(0.f, 0.f, 0.f, 0.f);
    for (int c = 0; c < C; ++c) {
      float4 v = pred4[(size_t)(g * 32 + c) * 64 + 32 + l];
      sm.x += v.x; sm.y += v.y; sm.z += v.z; sm.w += v.w;
    }
    float inv = 1.0f / (float)K;
    float4 o = out4[g * 64 + 32 + l];
    o.x += sm.x * inv; o.y += sm.y * inv; o.z += sm.z * inv; o.w += sm.w * inv;
    out4[g * 64 + 32 + l] = o;
  }
}

// ---------------------------------------------------------------------------
// fused relabel + count for next layer (cnt zeroed by topk)
// ---------------------------------------------------------------------------

__global__ __launch_bounds__(256) void relabel_count_kernel(
    const int* __restrict__ in_r, const int* __restrict__ in_c,
    int* __restrict__ out_r, int* __restrict__ out_c,
    const int* __restrict__ newid, int* __restrict__ cnt) {
  int e = blockIdx.x * 256 + threadIdx.x;
  int r = in_r[e];
  if (r < 0) {
    out_r[e] = -1;
    out_c[e] = -1;
    return;
  }
  int nr = newid[r];
  int nc = newid[in_c[e]];
  if (nr < 0 || nc < 0) {
    out_r[e] = -1;
    out_c[e] = -1;
  } else {
    out_r[e] = nr;
    out_c[e] = nc;
    atomicAdd(&cnt[nc], 1);
  }
}

// ---------------------------------------------------------------------------
// launch
// ---------------------------------------------------------------------------

extern "C" void kernel_launch(void* const* d_in, const int* in_sizes, int n_in,
                              void* d_out, int out_size, void* d_ws, size_t ws_size,
                              hipStream_t stream) {
  const float* x0 = (const float*)d_in[0];
  const int* erow = (const int*)d_in[1];
  const int* ecol = (const int*)d_in[2];
  const float* Wm[3] = {(const float*)d_in[3], (const float*)d_in[6], (const float*)d_in[9]};
  const float* bm[3] = {(const float*)d_in[4], (const float*)d_in[7], (const float*)d_in[10]};
  const float* pm[3] = {(const float*)d_in[5], (const float*)d_in[8], (const float*)d_in[11]};

  char* w = (char*)d_ws;
  size_t off = 0;
  auto alloc = [&](size_t bytes) -> void* {
    void* ptr = w + off;
    off = (off + bytes + 255) & ~(size_t)255;
    return ptr;
  };
  int* cur_row = (int*)alloc((size_t)NEDGE * 4);
  int* cur_col = (int*)alloc((size_t)NEDGE * 4);
  int2* meta16 = (int2*)alloc((size_t)NMAX * PRE * 8);
  int* srcext  = (int*)alloc((size_t)NMAX * CAP * 4);
  float* cfext = (float*)alloc((size_t)NMAX * CAP * 4);
  int* cnt     = (int*)alloc((size_t)NMAX * 4);
  int* cursor  = (int*)alloc((size_t)NMAX * 4);
  float* dinv  = (float*)alloc((size_t)NMAX * 4);
  int* newid   = (int*)alloc((size_t)NMAX * 4);
  float* score = (float*)alloc((size_t)NMAX * 4);
  int* sel     = (int*)alloc((size_t)BG * 512 * 4);
  float* tanhv = (float*)alloc((size_t)BG * 512 * 4);
  float* pn    = (float*)alloc(256);
  float* pred  = (float*)alloc((size_t)BG * 32 * 256 * 4);
  float* zh    = (float*)alloc((size_t)NMAX * HDIM * 4);
  float* x1    = (float*)alloc((size_t)BG * 512 * HDIM * 4);
  float* x2    = (float*)alloc((size_t)BG * 256 * HDIM * 4);
  float* x3    = (float*)alloc((size_t)BG * 128 * HDIM * 4);

  // allow >64 KB dynamic LDS for the agg kernel (L0 needs 148 KB)
  hipFuncSetAttribute((const void*)agg_lds_kernel,
                      hipFuncAttributeMaxDynamicSharedMemorySize, 152 * 1024);

  hipMemsetAsync(d_out, 0, (size_t)out_size * 4, stream);
  hipMemsetAsync(cnt, 0, (size_t)NMAX * 4, stream);
  pnorm_kernel<<<3, 128, 0, stream>>>(pm[0], pm[1], pm[2], pn);
  count_kernel<<<NEDGE / 256, 256, 0, stream>>>(ecol, cnt);

  const float* xin = x0;
  float* xout[3] = {x1, x2, x3};
  int Ps[3] = {1024, 512, 256};
  int LCs[3] = {5, 4, 3};     // log2(K/16)

  for (int L = 0; L < 3; ++L) {
    int P = Ps[L];
    int K = P >> 1;
    int n = BG * P;
    int lc = LCs[L];
    int C = 1 << lc;
    const int* in_r = (L == 0) ? erow : cur_row;
    const int* in_c = (L == 0) ? ecol : cur_col;
    size_t ldsBytes = (size_t)(P * 32 + P) * 4 + 16384;

    prep_kernel<<<n / 256, 256, 0, stream>>>(cnt, dinv, cursor, newid);
    fill_kernel<<<NEDGE / 256, 256, 0, stream>>>(in_r, in_c, dinv, cursor,
                                                 meta16, srcext, cfext, P - 1);
    agg_lds_kernel<<<BG * CHUNKS, 1024, ldsBytes, stream>>>(
        xin, zh, meta16, srcext, cfext, cursor, dinv, P);
    conv_kernel<<<n / 64, 256, 0, stream>>>(zh, Wm[L], bm[L], pm[L], score);
    topk_kernel<<<BG, P, 0, stream>>>(score, pn + L, sel, tanhv, newid, cnt, P, K);
    pool_gather_kernel<<<BG * C, 256, 0, stream>>>(zh, sel, tanhv, xout[L], pred, K, lc);
    pool_combine_kernel<<<BG, 64, 0, stream>>>(pred, (float*)d_out, K, C);
    if (L < 2) relabel_count_kernel<<<NEDGE / 256, 256, 0, stream>>>(
        in_r, in_c, cur_row, cur_col, newid, cnt);
    xin = xout[L];
  }
}